// Round 1
// baseline (1275.222 us; speedup 1.0000x reference)
//
#include <hip/hip_runtime.h>

// Tree-routed feed-forward (fast-feedforward) forward pass.
// x: [B, 1024] f32; keys/values: [4095, 8, 1024] f32; y: [B, 1024] f32.
// One block per sample; one wave per tree; 12-level data-dependent walk.

constexpr int D      = 1024;
constexpr int NTREES = 8;
constexpr int DEPTH  = 12;

__global__ __launch_bounds__(512)
void tree_ffn_kernel(const float* __restrict__ x,
                     const float* __restrict__ keys,
                     const float* __restrict__ values,
                     float* __restrict__ y)
{
    __shared__ float s_part[NTREES][D];   // 32 KiB: per-tree y partials

    const int b    = blockIdx.x;
    const int tid  = threadIdx.x;
    const int tree = tid >> 6;            // wave index == tree
    const int lane = tid & 63;

    // Load x[b] into registers, lane-strided so every load is coalesced:
    // xr[j] holds x[j*256 + lane*4 .. +3]
    const float4* xv = reinterpret_cast<const float4*>(x + (size_t)b * D);
    float4 xr[4];
#pragma unroll
    for (int j = 0; j < 4; ++j) xr[j] = xv[j * 64 + lane];

    float4 acc[4];
#pragma unroll
    for (int j = 0; j < 4; ++j) acc[j] = make_float4(0.f, 0.f, 0.f, 0.f);

    int node = 0;
    for (int level = 0; level < DEPTH; ++level) {
        const size_t base = ((size_t)node * NTREES + tree) * D;
        const float4* kv = reinterpret_cast<const float4*>(keys + base);
        const float4* vv = reinterpret_cast<const float4*>(values + base);

        // Issue key AND value loads together: value address depends only on
        // `node`, so the 8 dwordx4 loads overlap (halves serial latency).
        float4 kr[4], vr[4];
#pragma unroll
        for (int j = 0; j < 4; ++j) kr[j] = kv[j * 64 + lane];
#pragma unroll
        for (int j = 0; j < 4; ++j) vr[j] = vv[j * 64 + lane];

        // Per-lane partial dot (16 elements), then 64-lane butterfly reduce.
        float p = 0.f;
#pragma unroll
        for (int j = 0; j < 4; ++j) {
            p += xr[j].x * kr[j].x;
            p += xr[j].y * kr[j].y;
            p += xr[j].z * kr[j].z;
            p += xr[j].w * kr[j].w;
        }
#pragma unroll
        for (int m = 1; m < 64; m <<= 1) p += __shfl_xor(p, m, 64);
        const float lam = p;

#pragma unroll
        for (int j = 0; j < 4; ++j) {
            acc[j].x += lam * vr[j].x;
            acc[j].y += lam * vr[j].y;
            acc[j].z += lam * vr[j].z;
            acc[j].w += lam * vr[j].w;
        }
        node = node * 2 + 1 + (lam > 0.0f ? 1 : 0);
    }

    // Per-tree partials -> LDS, then cross-tree sum, coalesced store.
    float4* sp = reinterpret_cast<float4*>(&s_part[tree][0]);
#pragma unroll
    for (int j = 0; j < 4; ++j) sp[j * 64 + lane] = acc[j];
    __syncthreads();

    float* yout = y + (size_t)b * D;
    for (int e = tid; e < D; e += 512) {
        float s = 0.f;
#pragma unroll
        for (int w = 0; w < NTREES; ++w) s += s_part[w][e];
        yout[e] = s;
    }
}

extern "C" void kernel_launch(void* const* d_in, const int* in_sizes, int n_in,
                              void* d_out, int out_size, void* d_ws, size_t ws_size,
                              hipStream_t stream) {
    const float* x      = (const float*)d_in[0];
    const float* keys   = (const float*)d_in[1];
    const float* values = (const float*)d_in[2];
    float*       yout   = (float*)d_out;
    const int B = in_sizes[0] / D;   // 16384
    tree_ffn_kernel<<<B, 512, 0, stream>>>(x, keys, values, yout);
}

// Round 2
// 1185.944 us; speedup vs baseline: 1.0753x; 1.0753x over previous
//
#include <hip/hip_runtime.h>

// Tree-routed feed-forward forward pass, two-phase (route / accumulate).
// x: [B,1024] f32; keys/values: [4095, 8, 1024] f32; y: [B,1024] f32.
//
// Phase split rationale: keys(128MB)+x(64MB) < 256MB L3, values(128MB)+y(64MB)
// < 256MB L3, but all together (384MB) thrash L3 (round-1 FETCH=3.9GB).
// lam trace (B*8*12 f32 = 6MB) lives in d_ws; phase 2 recomputes the node
// walk from lam signs (bit-identical to phase 1).

constexpr int D      = 1024;
constexpr int NTREES = 8;
constexpr int DEPTH  = 12;

// ---------------- Phase 1: routing (keys only) ----------------
// One block per sample; wave w = tree w. x held in registers, butterfly dot.
__global__ __launch_bounds__(512)
void route_kernel(const float* __restrict__ x,
                  const float* __restrict__ keys,
                  float* __restrict__ lam_ws)
{
    const int b    = blockIdx.x;
    const int tid  = threadIdx.x;
    const int tree = tid >> 6;
    const int lane = tid & 63;

    const float4* xv = reinterpret_cast<const float4*>(x + (size_t)b * D);
    float4 xr[4];
#pragma unroll
    for (int j = 0; j < 4; ++j) xr[j] = xv[j * 64 + lane];

    float* lout = lam_ws + ((size_t)b * NTREES + tree) * DEPTH;

    int node = 0;
    for (int l = 0; l < DEPTH; ++l) {
        const float4* kv =
            reinterpret_cast<const float4*>(keys + ((size_t)node * NTREES + tree) * D);
        float p = 0.f;
#pragma unroll
        for (int j = 0; j < 4; ++j) {
            float4 k = kv[j * 64 + lane];
            p += xr[j].x * k.x + xr[j].y * k.y + xr[j].z * k.z + xr[j].w * k.w;
        }
#pragma unroll
        for (int m = 1; m < 64; m <<= 1) p += __shfl_xor(p, m, 64);
        if (lane == 0) lout[l] = p;
        node = node * 2 + 1 + (p > 0.0f ? 1 : 0);
    }
}

// ---------------- Phase 2: accumulate (values only) ----------------
// One block (256 thr) per sample; thread t owns y[b][4t..4t+3]. Node walk
// recomputed from lam signs; all 12 level-loads per tree are independent.
__global__ __launch_bounds__(256)
void accum_kernel(const float* __restrict__ values,
                  const float* __restrict__ lam_ws,
                  float* __restrict__ y)
{
    const int b   = blockIdx.x;
    const int tid = threadIdx.x;
    const int col = tid * 4;                 // float4 column slice

    float4 acc = make_float4(0.f, 0.f, 0.f, 0.f);
    const float* lb = lam_ws + (size_t)b * NTREES * DEPTH;

    for (int t = 0; t < NTREES; ++t) {
        float lam[DEPTH];
#pragma unroll
        for (int l = 0; l < DEPTH; ++l) lam[l] = lb[t * DEPTH + l];

        int node = 0;
#pragma unroll
        for (int l = 0; l < DEPTH; ++l) {
            const float4 v = *reinterpret_cast<const float4*>(
                values + ((size_t)node * NTREES + t) * D + col);
            acc.x += lam[l] * v.x;
            acc.y += lam[l] * v.y;
            acc.z += lam[l] * v.z;
            acc.w += lam[l] * v.w;
            node = node * 2 + 1 + (lam[l] > 0.0f ? 1 : 0);
        }
    }
    *reinterpret_cast<float4*>(y + (size_t)b * D + col) = acc;
}

// ---------------- Fallback: fused single kernel (round-1, passing) ----------
__global__ __launch_bounds__(512)
void tree_ffn_fused(const float* __restrict__ x,
                    const float* __restrict__ keys,
                    const float* __restrict__ values,
                    float* __restrict__ y)
{
    __shared__ float s_part[NTREES][D];

    const int b    = blockIdx.x;
    const int tid  = threadIdx.x;
    const int tree = tid >> 6;
    const int lane = tid & 63;

    const float4* xv = reinterpret_cast<const float4*>(x + (size_t)b * D);
    float4 xr[4];
#pragma unroll
    for (int j = 0; j < 4; ++j) xr[j] = xv[j * 64 + lane];

    float4 acc[4];
#pragma unroll
    for (int j = 0; j < 4; ++j) acc[j] = make_float4(0.f, 0.f, 0.f, 0.f);

    int node = 0;
    for (int level = 0; level < DEPTH; ++level) {
        const size_t base = ((size_t)node * NTREES + tree) * D;
        const float4* kv = reinterpret_cast<const float4*>(keys + base);
        const float4* vv = reinterpret_cast<const float4*>(values + base);
        float4 kr[4], vr[4];
#pragma unroll
        for (int j = 0; j < 4; ++j) kr[j] = kv[j * 64 + lane];
#pragma unroll
        for (int j = 0; j < 4; ++j) vr[j] = vv[j * 64 + lane];
        float p = 0.f;
#pragma unroll
        for (int j = 0; j < 4; ++j) {
            p += xr[j].x * kr[j].x + xr[j].y * kr[j].y +
                 xr[j].z * kr[j].z + xr[j].w * kr[j].w;
        }
#pragma unroll
        for (int m = 1; m < 64; m <<= 1) p += __shfl_xor(p, m, 64);
#pragma unroll
        for (int j = 0; j < 4; ++j) {
            acc[j].x += p * vr[j].x;
            acc[j].y += p * vr[j].y;
            acc[j].z += p * vr[j].z;
            acc[j].w += p * vr[j].w;
        }
        node = node * 2 + 1 + (p > 0.0f ? 1 : 0);
    }

    float4* sp = reinterpret_cast<float4*>(&s_part[tree][0]);
#pragma unroll
    for (int j = 0; j < 4; ++j) sp[j * 64 + lane] = acc[j];
    __syncthreads();

    float* yout = y + (size_t)b * D;
    for (int e = tid; e < D; e += 512) {
        float s = 0.f;
#pragma unroll
        for (int w = 0; w < NTREES; ++w) s += s_part[w][e];
        yout[e] = s;
    }
}

extern "C" void kernel_launch(void* const* d_in, const int* in_sizes, int n_in,
                              void* d_out, int out_size, void* d_ws, size_t ws_size,
                              hipStream_t stream) {
    const float* x      = (const float*)d_in[0];
    const float* keys   = (const float*)d_in[1];
    const float* values = (const float*)d_in[2];
    float*       yout   = (float*)d_out;
    const int B = in_sizes[0] / D;   // 16384

    const size_t lam_bytes = (size_t)B * NTREES * DEPTH * sizeof(float);
    if (ws_size >= lam_bytes) {
        float* lam_ws = (float*)d_ws;
        route_kernel<<<B, 512, 0, stream>>>(x, keys, lam_ws);
        accum_kernel<<<B, 256, 0, stream>>>(values, lam_ws, yout);
    } else {
        tree_ffn_fused<<<B, 512, 0, stream>>>(x, keys, values, yout);
    }
}

// Round 3
// 768.694 us; speedup vs baseline: 1.6589x; 1.5428x over previous
//
#include <hip/hip_runtime.h>
#include <hip/hip_bf16.h>

// Tree-routed feed-forward forward pass, bf16-staged two-phase.
// x: [B,1024] f32; keys/values: [4095, 8, 1024] f32; y: [B,1024] f32.
//
// Bottleneck (round-2 rocprof): both phases stream ~6.5 GB of gathered rows
// at the ~13 TB/s beyond-L2 fabric rate. Fix: halve stream volume with bf16
// mirrors of keys/values built in d_ws each launch. Routing stays fp32-exact
// via a recompute net: if |lam_bf16| < TAU (10 sigma of bf16 dot error),
// re-dot from the original fp32 keys (~1.6% of dots, wave-uniform branch).

constexpr int D      = 1024;
constexpr int NTREES = 8;
constexpr int DEPTH  = 12;
constexpr int NNODES = 4095;
constexpr float TAU  = 0.02f;

static constexpr size_t KV_ELEMS  = (size_t)NNODES * NTREES * D;   // 33,546,240

__device__ __forceinline__ float bf2f(unsigned short u) {
    return __uint_as_float(((unsigned int)u) << 16);
}
__device__ __forceinline__ unsigned short f2bf(float f) {
    __hip_bfloat16 h = __float2bfloat16(f);          // RNE
    return *reinterpret_cast<unsigned short*>(&h);
}

struct ushort4_t { unsigned short x, y, z, w; };

// ---------------- Convert: fp32 keys/values -> bf16 mirrors in ws ----------
__global__ __launch_bounds__(256)
void convert_kernel(const float* __restrict__ keys,
                    const float* __restrict__ values,
                    unsigned short* __restrict__ kb,
                    unsigned short* __restrict__ vb,
                    int do_keys)
{
    size_t i4 = ((size_t)blockIdx.x * blockDim.x + threadIdx.x) * 4;
    if (i4 >= KV_ELEMS) return;
    if (do_keys) {
        float4 k = *reinterpret_cast<const float4*>(keys + i4);
        ushort4_t ko{f2bf(k.x), f2bf(k.y), f2bf(k.z), f2bf(k.w)};
        *reinterpret_cast<ushort4_t*>(kb + i4) = ko;
    }
    float4 v = *reinterpret_cast<const float4*>(values + i4);
    ushort4_t vo{f2bf(v.x), f2bf(v.y), f2bf(v.z), f2bf(v.w)};
    *reinterpret_cast<ushort4_t*>(vb + i4) = vo;
}

// ---------------- Phase 1: routing, bf16 keys + fp32 recompute net ---------
__global__ __launch_bounds__(512)
void route_bf16_kernel(const float* __restrict__ x,
                       const float* __restrict__ keys_f32,
                       const unsigned short* __restrict__ kb,
                       float* __restrict__ lam_ws)
{
    const int b    = blockIdx.x;
    const int tid  = threadIdx.x;
    const int tree = tid >> 6;
    const int lane = tid & 63;

    const float4* xv = reinterpret_cast<const float4*>(x + (size_t)b * D);
    float4 xr[4];
#pragma unroll
    for (int j = 0; j < 4; ++j) xr[j] = xv[j * 64 + lane];

    float* lout = lam_ws + ((size_t)b * NTREES + tree) * DEPTH;

    int node = 0;
    for (int l = 0; l < DEPTH; ++l) {
        const size_t rbase = ((size_t)node * NTREES + tree) * D;
        const unsigned short* row = kb + rbase;
        float p = 0.f;
#pragma unroll
        for (int j = 0; j < 4; ++j) {
            ushort4_t u = *reinterpret_cast<const ushort4_t*>(row + j * 256 + lane * 4);
            p += xr[j].x * bf2f(u.x) + xr[j].y * bf2f(u.y) +
                 xr[j].z * bf2f(u.z) + xr[j].w * bf2f(u.w);
        }
#pragma unroll
        for (int m = 1; m < 64; m <<= 1) p += __shfl_xor(p, m, 64);

        if (fabsf(p) < TAU) {   // wave-uniform: p identical across lanes
            const float4* kv = reinterpret_cast<const float4*>(keys_f32 + rbase);
            float q = 0.f;
#pragma unroll
            for (int j = 0; j < 4; ++j) {
                float4 k = kv[j * 64 + lane];
                q += xr[j].x * k.x + xr[j].y * k.y + xr[j].z * k.z + xr[j].w * k.w;
            }
#pragma unroll
            for (int m = 1; m < 64; m <<= 1) q += __shfl_xor(q, m, 64);
            p = q;
        }

        if (lane == 0) lout[l] = p;
        node = node * 2 + 1 + (p > 0.0f ? 1 : 0);
    }
}

// ---------------- Phase 2: accumulate from bf16 values ---------------------
__global__ __launch_bounds__(256)
void accum_bf16_kernel(const unsigned short* __restrict__ vb,
                       const float* __restrict__ lam_ws,
                       float* __restrict__ y)
{
    const int b   = blockIdx.x;
    const int tid = threadIdx.x;
    const int col = tid * 4;

    float4 acc = make_float4(0.f, 0.f, 0.f, 0.f);
    const float* lb = lam_ws + (size_t)b * NTREES * DEPTH;

    for (int t = 0; t < NTREES; ++t) {
        float lam[DEPTH];
#pragma unroll
        for (int l = 0; l < DEPTH; ++l) lam[l] = lb[t * DEPTH + l];

        int node = 0;
#pragma unroll
        for (int l = 0; l < DEPTH; ++l) {
            ushort4_t u = *reinterpret_cast<const ushort4_t*>(
                vb + ((size_t)node * NTREES + t) * D + col);
            acc.x += lam[l] * bf2f(u.x);
            acc.y += lam[l] * bf2f(u.y);
            acc.z += lam[l] * bf2f(u.z);
            acc.w += lam[l] * bf2f(u.w);
            node = node * 2 + 1 + (lam[l] > 0.0f ? 1 : 0);
        }
    }
    *reinterpret_cast<float4*>(y + (size_t)b * D + col) = acc;
}

// ---------------- fp32 fallbacks (round-2, verified passing) ---------------
__global__ __launch_bounds__(512)
void route_kernel(const float* __restrict__ x,
                  const float* __restrict__ keys,
                  float* __restrict__ lam_ws)
{
    const int b    = blockIdx.x;
    const int tid  = threadIdx.x;
    const int tree = tid >> 6;
    const int lane = tid & 63;

    const float4* xv = reinterpret_cast<const float4*>(x + (size_t)b * D);
    float4 xr[4];
#pragma unroll
    for (int j = 0; j < 4; ++j) xr[j] = xv[j * 64 + lane];

    float* lout = lam_ws + ((size_t)b * NTREES + tree) * DEPTH;

    int node = 0;
    for (int l = 0; l < DEPTH; ++l) {
        const float4* kv =
            reinterpret_cast<const float4*>(keys + ((size_t)node * NTREES + tree) * D);
        float p = 0.f;
#pragma unroll
        for (int j = 0; j < 4; ++j) {
            float4 k = kv[j * 64 + lane];
            p += xr[j].x * k.x + xr[j].y * k.y + xr[j].z * k.z + xr[j].w * k.w;
        }
#pragma unroll
        for (int m = 1; m < 64; m <<= 1) p += __shfl_xor(p, m, 64);
        if (lane == 0) lout[l] = p;
        node = node * 2 + 1 + (p > 0.0f ? 1 : 0);
    }
}

__global__ __launch_bounds__(256)
void accum_kernel(const float* __restrict__ values,
                  const float* __restrict__ lam_ws,
                  float* __restrict__ y)
{
    const int b   = blockIdx.x;
    const int tid = threadIdx.x;
    const int col = tid * 4;

    float4 acc = make_float4(0.f, 0.f, 0.f, 0.f);
    const float* lb = lam_ws + (size_t)b * NTREES * DEPTH;

    for (int t = 0; t < NTREES; ++t) {
        float lam[DEPTH];
#pragma unroll
        for (int l = 0; l < DEPTH; ++l) lam[l] = lb[t * DEPTH + l];

        int node = 0;
#pragma unroll
        for (int l = 0; l < DEPTH; ++l) {
            const float4 v = *reinterpret_cast<const float4*>(
                values + ((size_t)node * NTREES + t) * D + col);
            acc.x += lam[l] * v.x;
            acc.y += lam[l] * v.y;
            acc.z += lam[l] * v.z;
            acc.w += lam[l] * v.w;
            node = node * 2 + 1 + (lam[l] > 0.0f ? 1 : 0);
        }
    }
    *reinterpret_cast<float4*>(y + (size_t)b * D + col) = acc;
}

extern "C" void kernel_launch(void* const* d_in, const int* in_sizes, int n_in,
                              void* d_out, int out_size, void* d_ws, size_t ws_size,
                              hipStream_t stream) {
    const float* x      = (const float*)d_in[0];
    const float* keys   = (const float*)d_in[1];
    const float* values = (const float*)d_in[2];
    float*       yout   = (float*)d_out;
    const int B = in_sizes[0] / D;   // 16384

    const size_t bf_bytes  = KV_ELEMS * sizeof(unsigned short);      // 67.1 MB
    const size_t lam_bytes = (size_t)B * NTREES * DEPTH * sizeof(float); // 6.3 MB
    const int conv_blocks  = (int)((KV_ELEMS / 4 + 255) / 256);      // 32760

    char* ws = (char*)d_ws;

    if (ws_size >= 2 * bf_bytes + lam_bytes) {
        // Tier A: bf16 keys (+fp32 recompute net) and bf16 values.
        unsigned short* kb = (unsigned short*)ws;
        unsigned short* vb = (unsigned short*)(ws + bf_bytes);
        float* lam_ws      = (float*)(ws + 2 * bf_bytes);
        convert_kernel<<<conv_blocks, 256, 0, stream>>>(keys, values, kb, vb, 1);
        route_bf16_kernel<<<B, 512, 0, stream>>>(x, keys, kb, lam_ws);
        accum_bf16_kernel<<<B, 256, 0, stream>>>(vb, lam_ws, yout);
    } else if (ws_size >= bf_bytes + lam_bytes) {
        // Tier B: fp32 routing, bf16 values only.
        unsigned short* vb = (unsigned short*)ws;
        float* lam_ws      = (float*)(ws + bf_bytes);
        convert_kernel<<<conv_blocks, 256, 0, stream>>>(keys, values, vb, vb, 0);
        route_kernel<<<B, 512, 0, stream>>>(x, keys, lam_ws);
        accum_bf16_kernel<<<B, 256, 0, stream>>>(vb, lam_ws, yout);
    } else {
        // Tier C: fp32 two-phase (round-2 verified path).
        float* lam_ws = (float*)ws;
        route_kernel<<<B, 512, 0, stream>>>(x, keys, lam_ws);
        accum_kernel<<<B, 256, 0, stream>>>(values, lam_ws, yout);
    }
}